// Round 13
// baseline (139.905 us; speedup 1.0000x reference)
//
#include <hip/hip_runtime.h>

#define S_ROWS 524288
#define D_COLS 63
#define BLOCK 256
#define GRID 2048                 // 8192 waves x 64 rows
#define ROWS_PER_WAVE 64
#define ITERS 8                   // 8 rows per iteration per wave
#define BUF_F4 132                // 528 floats/array/buffer (max read idx 513)
#define NACC 30
#define POSW 0.2f
#define NEG_INF (-__builtin_huge_valf())

#define F_CUB  1u
#define F_CUB2 2u
#define F_AP   4u
#define F_REF  8u
#define F_TR   16u
#define F_SQ   32u

enum {
  A_CMD_LOSS = 0, A_CMDC, A_MAE1, A_MAE2, A_MAE4, A_MAE5,
  A_CE_AP, A_CUBC,
  A_REF_AX_CE, A_REF_CUB_CE, A_REF_AXC, A_REF_CUBC,
  A_TR_AX_CE, A_TR_CUB_CE, A_TR_AXC, A_TR_CUBC,
  A_SQ_CUB_CE, A_FACE_CE, A_SQ_CUBC, A_FACEC,
  A_BCE, A_NPOS, A_NNEG, A_POSC, A_NEGC,
  A_NA, A_NC, A_NREF, A_NTR, A_NSQ
};

#define GLOAD_LDS16(gptr, lptr) \
  __builtin_amdgcn_global_load_lds( \
      (const __attribute__((address_space(1))) void*)(gptr), \
      (__attribute__((address_space(3))) void*)(lptr), 16, 0, 0)

__device__ __forceinline__ float logsig(float x) {
  float ax = fabsf(x);
  return fminf(x, 0.f) - __logf(1.f + __expf(-ax));
}

__global__ void init_ws(float* ws) {
  int i = threadIdx.x;
  if (i < NACC) ws[i] = 0.f;
  unsigned* wu = (unsigned*)ws;
  if (i == NACC) wu[NACC] = 0xFFFFFFFFu;
  if (i == NACC + 1) wu[NACC + 1] = 0u;
}

__launch_bounds__(BLOCK, 3)
__global__ void prog_loss_main(const float* __restrict__ P,
                               const float* __restrict__ T,
                               const float* __restrict__ W,
                               float* __restrict__ ws) {
  // wave-private double-buffered 8-row tiles: [wave][buf][array P/T/W][f4]
  __shared__ float4 sbuf[4][2][3][BUF_F4];
  __shared__ float sred[4][NACC];
  __shared__ unsigned sflags[4];
  __shared__ unsigned smin[4];

  const int tid = threadIdx.x;
  const int lane = tid & 63;
  const int wave = tid >> 6;
  const int k = lane & 7;   // slice-lane within row
  const int g = lane >> 3;  // row within the 8-row group
  const int wid = blockIdx.x * 4 + wave;

  // loop-invariant per-lane slice geometry
  const int st = (k == 0) ? 0 : (k == 1) ? 7 : (k == 2) ? 18 : (k == 3) ? 29
               : (k == 4) ? 40 : (k == 5) ? 49 : (k == 6) ? 54 : 62;
  const int ln = (k == 0) ? 7 : (k == 1) ? 11 : (k == 2) ? 11 : (k == 3) ? 11
               : (k == 4) ? 9 : (k == 5) ? 5 : (k == 6) ? 8 : 1;
  const int cl = (k == 0) ? 7 : (k == 1) ? 11 : (k == 2) ? 11 : (k == 3) ? 11
               : (k == 4) ? 0 : (k == 5) ? 3 : (k == 6) ? 6 : 0;
  const int idx0 = g * D_COLS + st;
  // loop-invariant lane predicates (branchless accumulation)
  const bool k0 = (k == 0), k1 = (k == 1), k2 = (k == 2), k3 = (k == 3),
             k5 = (k == 5), k6 = (k == 6), k7 = (k == 7);
  // loop-invariant shuffle sources (k0/k2/k3 lanes of this row group)
  const int s_cmd = g << 3;
  const int s_okC = (g << 3) | 2;
  const int s_okD = (g << 3) | 3;

  float acc[NACC];
  #pragma unroll
  for (int v = 0; v < NACC; ++v) acc[v] = 0.f;
  unsigned fl = 0u;
  unsigned mymin = 0xFFFFFFFFu;

  // ---- wave-private staging: 6 x global_load_lds (f4-coalesced, 1KB/instr) ----
  auto stage = [&](int b, int it) {
    const size_t f4b = (size_t)wid * 1008 + (size_t)it * 126;  // (row0*63)/4
    const float4* P4 = (const float4*)P + f4b;
    const float4* T4 = (const float4*)T + f4b;
    const float4* W4 = (const float4*)W + f4b;
    float4* bp = &sbuf[wave][b][0][0];
    float4* bt = &sbuf[wave][b][1][0];
    float4* bw = &sbuf[wave][b][2][0];
    GLOAD_LDS16(&P4[lane], bp);
    GLOAD_LDS16(&T4[lane], bt);
    GLOAD_LDS16(&W4[lane], bw);
    if (lane < 62) {
      GLOAD_LDS16(&P4[64 + lane], bp + 64);
      GLOAD_LDS16(&T4[64 + lane], bt + 64);
      GLOAD_LDS16(&W4[64 + lane], bw + 64);
    }
  };

  stage(0, 0);  // prologue

  #pragma unroll 1
  for (int it = 0; it < ITERS; ++it) {
    const int b = it & 1;
    if (it + 1 < ITERS) {
      stage(b ^ 1, it + 1);
      asm volatile("s_waitcnt vmcnt(6)" ::: "memory");  // current ready; next in flight
    } else {
      asm volatile("s_waitcnt vmcnt(0)" ::: "memory");
    }
    __builtin_amdgcn_sched_barrier(0);

    const float* lp = (const float*)&sbuf[wave][b][0][0];
    const float* lt = (const float*)&sbuf[wave][b][1][0];
    const float* lw = (const float*)&sbuf[wave][b][2][0];

    float pv[11], tv[11], wv[11];
    #pragma unroll
    for (int j = 0; j < 11; ++j) {
      pv[j] = lp[idx0 + j];
      tv[j] = lt[idx0 + j];
      wv[j] = lw[idx0 + j];
    }

    // lane-local CE scan, NaN-safe select masking (j < cl)
    float tmax = NEG_INF, pmax = NEG_INF, p_at = 0.f;
    int targ = -1, pidx = -1;
    #pragma unroll
    for (int j = 0; j < 11; ++j) {
      float te = (j < cl) ? tv[j] : NEG_INF;
      float pe = (j < cl) ? pv[j] : NEG_INF;
      bool u = te > tmax;
      tmax = u ? te : tmax;
      targ = u ? j : targ;
      p_at = u ? pv[j] : p_at;
      bool v2 = pe > pmax;
      pmax = v2 ? pe : pmax;
      pidx = v2 ? j : pidx;
    }
    float s = 0.f;
    #pragma unroll
    for (int j = 0; j < 11; ++j) {
      float e = __expf(pv[j] - pmax);
      s += (j < cl) ? e : 0.f;
    }
    float ce = pmax + __logf(s) - p_at;   // NaN for cl==0 lanes; always select-gated
    bool ok = (pidx == targ);

    // lane-local masked MAE (j < ln)
    float mae = 0.f;
    #pragma unroll
    for (int j = 0; j < 11; ++j) {
      float d = wv[j] * fabsf(pv[j] - tv[j]);
      mae += (j < ln) ? d : 0.f;
    }

    // cross-lane glue (loop-invariant sources)
    int c    = __shfl(targ, s_cmd, 64);
    int okCv = __shfl((int)ok, s_okC, 64);
    int okDv = __shfl((int)ok, s_okD, 64);
    bool okC = okCv != 0, okD = okDv != 0;
    const unsigned gr = (unsigned)(wid * ROWS_PER_WAVE + it * 8 + g);
    const bool c1 = (c == 1), c2 = (c == 2), c3 = (c == 3), c4 = (c == 4), c5 = (c == 5);

    // ---------- fully branchless accumulation ----------
    acc[A_MAE1] += c1 ? mae : 0.f;
    acc[A_MAE2] += c2 ? mae : 0.f;
    acc[A_MAE4] += c4 ? mae : 0.f;
    acc[A_MAE5] += c5 ? mae : 0.f;

    acc[A_CMD_LOSS] += k0 ? ce : 0.f;
    acc[A_CMDC]     += (k0 && ok) ? 1.f : 0.f;
    acc[A_NC]   += (k0 && c1) ? 1.f : 0.f;
    acc[A_NA]   += (k0 && c2) ? 1.f : 0.f;
    acc[A_NREF] += (k0 && c3) ? 1.f : 0.f;
    acc[A_NTR]  += (k0 && c4) ? 1.f : 0.f;
    acc[A_NSQ]  += (k0 && c5) ? 1.f : 0.f;

    acc[A_CE_AP]      += ((k1 || k2) && c2) ? ce : 0.f;
    acc[A_CUBC]       += (k1 && c2 && ok && okC) ? 1.f : 0.f;
    acc[A_REF_CUB_CE] += (k1 && c3) ? ce : 0.f;
    acc[A_REF_CUBC]   += (k1 && c3 && ok) ? 1.f : 0.f;
    acc[A_TR_CUB_CE]  += (k1 && c4) ? ce : 0.f;
    acc[A_TR_CUBC]    += (k1 && c4 && ok) ? 1.f : 0.f;
    acc[A_SQ_CUB_CE]  += ((k1 || k2 || k3) && c5) ? ce : 0.f;
    acc[A_SQ_CUBC]    += (k1 && c5 && ok && okC && okD) ? 1.f : 0.f;
    acc[A_REF_AX_CE]  += (k5 && c3) ? ce : 0.f;
    acc[A_REF_AXC]    += (k5 && c3 && ok) ? 1.f : 0.f;
    acc[A_TR_AX_CE]   += (k5 && c4) ? ce : 0.f;
    acc[A_TR_AXC]     += (k5 && c4 && ok) ? 1.f : 0.f;
    acc[A_FACE_CE]    += (k6 && c5) ? ce : 0.f;
    acc[A_FACEC]      += (k6 && c5 && ok) ? 1.f : 0.f;

    // BCE (k7 lane's pv[0]/tv[0] are col 62); computed unconditionally, gated by select
    {
      float x62 = pv[0], t62 = tv[0];
      float bce = -(POSW * t62 * logsig(x62) + (1.f - t62) * logsig(-x62));
      bool bg = k7 && c1;
      bool pos = (t62 == 1.f), neg = (t62 == 0.f);
      acc[A_BCE]  += bg ? bce : 0.f;
      acc[A_NPOS] += (bg && pos) ? 1.f : 0.f;
      acc[A_NNEG] += (bg && neg) ? 1.f : 0.f;
      acc[A_POSC] += (bg && pos && x62 > 0.f) ? 1.f : 0.f;
      acc[A_NEGC] += (bg && neg && x62 <= 0.f) ? 1.f : 0.f;
    }

    // gates + first-cub-row (k0 lanes only, branchless)
    {
      bool f = k0 && c1;
      fl |= (f && gr >= 1u) ? F_CUB : 0u;
      fl |= (f && gr >= 2u) ? F_CUB2 : 0u;
      fl |= (k0 && c2 && gr >= 1u) ? F_AP : 0u;
      fl |= (k0 && c3 && gr >= 1u) ? F_REF : 0u;
      fl |= (k0 && c4 && gr >= 1u) ? F_TR : 0u;
      fl |= (k0 && c5 && gr >= 1u) ? F_SQ : 0u;
      unsigned cand = f ? gr : 0xFFFFFFFFu;
      mymin = (cand < mymin) ? cand : mymin;
    }
  }

  // ---- reduction: wave shuffle -> LDS -> atomics ----
  #pragma unroll
  for (int v = 0; v < NACC; ++v) {
    float x = acc[v];
    #pragma unroll
    for (int off = 32; off > 0; off >>= 1) x += __shfl_down(x, off, 64);
    if (lane == 0) sred[wave][v] = x;
  }
  {
    unsigned f = fl, m = mymin;
    #pragma unroll
    for (int off = 32; off > 0; off >>= 1) {
      f |= __shfl_down(f, off, 64);
      unsigned om = __shfl_down(m, off, 64);
      m = (om < m) ? om : m;
    }
    if (lane == 0) { sflags[wave] = f; smin[wave] = m; }
  }
  __syncthreads();
  unsigned* wu = (unsigned*)ws;
  if (tid == 0) {
    unsigned f = sflags[0] | sflags[1] | sflags[2] | sflags[3];
    unsigned m = min(min(smin[0], smin[1]), min(smin[2], smin[3]));
    if (f) atomicOr(&wu[NACC + 1], f);
    if (m != 0xFFFFFFFFu) atomicMin(&wu[NACC], m);
  }
  if (tid < NACC) {
    float s = sred[0][tid] + sred[1][tid] + sred[2][tid] + sred[3][tid];
    if (s != 0.f) atomicAdd(&ws[tid], s);
  }
}

__global__ void finalize_k(const float* __restrict__ ws,
                           const float* __restrict__ P,
                           const float* __restrict__ T,
                           float* __restrict__ out) {
  const unsigned* wu = (const unsigned*)ws;
  unsigned flags = wu[NACC + 1];
  unsigned fm = wu[NACC];
  bool g_cub  = (flags & F_CUB)  != 0;
  bool g_cub2 = (flags & F_CUB2) != 0;
  bool g_ap   = (flags & F_AP)   != 0;
  bool g_ref  = (flags & F_REF)  != 0;
  bool g_tr   = (flags & F_TR)   != 0;
  bool g_sq   = (flags & F_SQ)   != 0;
  unsigned first = (fm == 0xFFFFFFFFu) ? 0u : fm;
  float x62 = P[(size_t)first * D_COLS + 62];
  float t62 = T[(size_t)first * D_COLS + 62];
  float bce_f = -(POSW * t62 * logsig(x62) + (1.f - t62) * logsig(-x62));
  float pos_f  = (t62 == 1.f) ? 1.f : 0.f;
  float neg_f  = (t62 == 0.f) ? 1.f : 0.f;
  float posc_f = (t62 == 1.f && x62 > 0.f) ? 1.f : 0.f;
  float negc_f = (t62 == 0.f && x62 <= 0.f) ? 1.f : 0.f;

  out[0]  = ws[A_CMD_LOSS];
  out[1]  = g_cub ? ws[A_MAE1] : 0.f;
  out[2]  = g_ap  ? ws[A_MAE2] : 0.f;
  out[3]  = g_sq  ? ws[A_MAE5] : 0.f;
  out[4]  = g_tr  ? ws[A_MAE4] : 0.f;
  out[5]  = g_ap  ? ws[A_CE_AP] : 0.f;
  out[6]  = g_sq  ? ws[A_SQ_CUB_CE] : 0.f;
  out[7]  = (g_ref ? ws[A_REF_CUB_CE] : 0.f) + (g_tr ? ws[A_TR_CUB_CE] : 0.f);
  out[8]  = (g_ref ? ws[A_REF_AX_CE]  : 0.f) + (g_tr ? ws[A_TR_AX_CE]  : 0.f);
  out[9]  = g_sq ? ws[A_FACE_CE] : 0.f;
  out[10] = ws[A_CMDC];
  out[11] = g_ap ? ws[A_CUBC] : 0.f;
  out[12] = g_sq ? ws[A_SQ_CUBC] : 0.f;
  out[13] = (g_ref ? ws[A_REF_CUBC] : 0.f) + (g_tr ? ws[A_TR_CUBC] : 0.f);
  out[14] = (g_ref ? ws[A_REF_AXC]  : 0.f) + (g_tr ? ws[A_TR_AXC]  : 0.f);
  out[15] = g_sq ? ws[A_FACEC] : 0.f;
  out[16] = g_cub2 ? (ws[A_BCE]  - bce_f)  : 0.f;
  out[17] = g_cub2 ? (ws[A_POSC] - posc_f) : 0.f;
  out[18] = g_cub2 ? (ws[A_NEGC] - negc_f) : 0.f;
  out[19] = g_cub2 ? (ws[A_NNEG] - neg_f)  : 0.f;
  out[20] = g_cub2 ? (ws[A_NPOS] - pos_f)  : 0.f;
  out[21] = ws[A_NA];
  out[22] = ws[A_NC];
  out[23] = ws[A_NREF] + ws[A_NTR];
  out[24] = ws[A_NSQ];
}

extern "C" void kernel_launch(void* const* d_in, const int* in_sizes, int n_in,
                              void* d_out, int out_size, void* d_ws, size_t ws_size,
                              hipStream_t stream) {
  const float* P = (const float*)d_in[0];
  const float* T = (const float*)d_in[1];
  const float* W = (const float*)d_in[2];
  float* ws = (float*)d_ws;
  float* out = (float*)d_out;

  hipLaunchKernelGGL(init_ws, dim3(1), dim3(64), 0, stream, ws);
  hipLaunchKernelGGL(prog_loss_main, dim3(GRID), dim3(BLOCK), 0, stream, P, T, W, ws);
  hipLaunchKernelGGL(finalize_k, dim3(1), dim3(1), 0, stream, ws, P, T, out);
}